// Round 8
// baseline (135.896 us; speedup 1.0000x reference)
//
#include <hip/hip_runtime.h>

typedef __attribute__((ext_vector_type(8))) short short8;
typedef __attribute__((ext_vector_type(4))) float f32x4;

#define BB 64
#define TS 2000
#define NN (TS*160)
#define MB 48
#define TB 42            // ceil(2000/48)
#define NTH 640          // 10 waves: wave = output col-tile ct
#define EPS_LOG 1.52587890625e-05f   // 2^-16

// ws layout: ushort (bf16) region then float region
#define W1F_U 0          // 40960 ushorts: [tap][ct10][kp16][col16][8]
#define W1T_U 40960      // 20480 ushorts: [tap][ct10][kp8][col16][8] (k>=41 zero)
#define W2_U  61440      // 51200 ushorts: [tap][ct10][kp20][col16][8]
#define B1C_F 56320      // float idx: b1f+b1t (160)
#define B2C_F 56480      // float idx: b2 (160)

// XOR bank-swizzle keys (ushort units; 16-us = 32B granules, bit3 = 16B)
#define KF(r) (((r)&7)<<4)                       // feat rows (128 us)
#define KT(r) (((((r)&3)<<4)) | ((((r)&4))<<1))  // tenv rows (64 us)
#define KA(r) (((r)&7)<<4)                       // hidA rows (128 us)
#define KB(r) (((((r)&3)<<4)) | ((((r)&4))<<1))  // hidB rows (64 us)

__device__ __forceinline__ unsigned short f2bf(float f) {
    union { float f; unsigned u; } v; v.f = f;
    unsigned r = v.u + 0x7FFF + ((v.u >> 16) & 1);   // RNE
    return (unsigned short)(r >> 16);
}

__global__ void repack(const float* __restrict__ W1f, const float* __restrict__ b1f,
                       const float* __restrict__ W1t, const float* __restrict__ b1t,
                       const float* __restrict__ W2,  const float* __restrict__ b2,
                       void* wsv) {
    unsigned short* wu = (unsigned short*)wsv;
    float* wf = (float*)wsv;
    int n = blockIdx.x * 256 + threadIdx.x;
    if (n < 40960) {                       // W1f
        int tap = n / 20480, m = n % 20480;
        int ct = m / 2048, m2 = m % 2048;
        int kp = m2 / 128, col = (m2 % 128) / 8, i = m2 % 8;
        int o = ct * 16 + col, c = kp * 8 + i;
        wu[W1F_U + n] = f2bf(W1f[(o * 128 + c) * 2 + tap]);
    } else if (n < 61440) {                // W1t (K padded to 64)
        int r = n - 40960;
        int tap = r / 10240, m = r % 10240;
        int ct = m / 1024, m2 = m % 1024;
        int kp = m2 / 128, col = (m2 % 128) / 8, i = m2 % 8;
        int o = ct * 16 + col, c = kp * 8 + i;
        wu[W1T_U + r] = (c < 41) ? f2bf(W1t[(o * 41 + c) * 2 + tap]) : (unsigned short)0;
    } else if (n < 112640) {               // W2
        int r = n - 61440;
        int tap = r / 25600, m = r % 25600;
        int ct = m / 2560, m2 = m % 2560;
        int kp = m2 / 128, col = (m2 % 128) / 8, i = m2 % 8;
        int o = ct * 16 + col, c = kp * 8 + i;
        wu[W2_U + r] = f2bf(W2[(o * 160 + c) * 2 + tap]);
    } else if (n < 112800) {               // b1 combined
        int o = n - 112640;
        wf[B1C_F + o] = b1f[o] + b1t[o];
    } else if (n < 112960) {               // b2 copy
        int o = n - 112800;
        wf[B2C_F + o] = b2[o];
    }
}

__global__ __launch_bounds__(NTH) void td_main(
    const float* __restrict__ x,
    const float* __restrict__ feat,
    const unsigned short* __restrict__ wu,
    const float* __restrict__ wf,
    float* __restrict__ out)
{
    // power-of-2 row strides + XOR swizzle -> <=2-way bank aliasing on b128 reads
    __shared__ __align__(16) unsigned short s_feat[65 * 128]; // row r <-> t = t0-17+r
    __shared__ __align__(16) unsigned short s_tenv[65 * 64];  // cols 0..40 data, 41..63 zero
    __shared__ __align__(16) unsigned short s_hidA[64 * 128]; // ch 0..127, row h <-> t = t0-16+h
    __shared__ __align__(16) unsigned short s_hidB[64 * 64];  // ch 128..159 at col 0..31

    const int tid  = threadIdx.x;
    const int b    = blockIdx.y;
    const int t0   = blockIdx.x * MB;
    const int wid  = tid >> 6;    // 0..9 = ct (wave-stationary output col-tile)
    const int lane = tid & 63;
    const int lr   = lane & 15;   // A row within tile / D col
    const int lk   = lane >> 4;   // k-group / D row-group
    const int ct   = wid;

    // ---- weight prologue: register-stationary for the whole block ----
    short8 wB0[6], wB1[6];   // stage B: s=0..3 feat-taps, s=4..5 tenv-taps
    {
        const unsigned short* bf0 = wu + W1F_U + ct * 2048 + lk * 128 + lr * 8;
        const unsigned short* bt0 = wu + W1T_U + ct * 1024 + lk * 128 + lr * 8;
#pragma unroll
        for (int s = 0; s < 4; ++s) {
            wB0[s] = *(const short8*)(bf0 + s * 512);
            wB1[s] = *(const short8*)(bf0 + 20480 + s * 512);
        }
#pragma unroll
        for (int s = 0; s < 2; ++s) {
            wB0[4 + s] = *(const short8*)(bt0 + s * 512);
            wB1[4 + s] = *(const short8*)(bt0 + 10240 + s * 512);
        }
    }
    short8 wC0[5], wC1[5];
    {
        const unsigned short* b2p = wu + W2_U + ct * 2560 + lk * 128 + lr * 8;
#pragma unroll
        for (int s = 0; s < 5; ++s) {
            wC0[s] = *(const short8*)(b2p + s * 512);
            wC1[s] = *(const short8*)(b2p + 25600 + s * 512);
        }
    }
    const float bias1 = wf[B1C_F + ct * 16 + lr];
    const float bias2 = wf[B2C_F + ct * 16 + lr];

    // ---- stage features -> bf16 LDS (swizzled) ----
    const float4* feat4 = (const float4*)feat;
    for (int idx = tid; idx < 65 * 32; idx += NTH) {
        int r = idx >> 5, c4 = idx & 31;
        int t = t0 - 17 + r;
        float4 v = make_float4(0.f, 0.f, 0.f, 0.f);
        if (t >= 0 && t < TS) v = feat4[((size_t)b * TS + t) * 32 + c4];
        ushort4 h;
        h.x = f2bf(v.x); h.y = f2bf(v.y); h.z = f2bf(v.z); h.w = f2bf(v.w);
        *(ushort4*)&s_feat[r * 128 + ((c4 * 4) ^ KF(r))] = h;
    }

    // ---- envelope -> tenv (half-wave per row, shuffle reduce; swizzled) ----
    {
        const int hw = tid >> 5;     // 0..19
        const int hl = tid & 31;
        for (int r = hw; r < 65; r += NTH / 32) {
            int t = t0 - 17 + r;
            const int kt = KT(r);
            if (t >= 0 && t < TS) {
                const float4* xr = (const float4*)(x + (size_t)b * NN + (size_t)t * 160);
                float4 v = xr[hl];
                float e1 = __logf(0.25f * (fabsf(v.x) + fabsf(v.y) + fabsf(v.z) + fabsf(v.w)) + EPS_LOG);
                float e2 = 0.f;
                if (hl < 8) {
                    float4 u = xr[hl + 32];
                    e2 = __logf(0.25f * (fabsf(u.x) + fabsf(u.y) + fabsf(u.z) + fabsf(u.w)) + EPS_LOG);
                }
                float s = e1 + e2;
#pragma unroll
                for (int m = 16; m; m >>= 1) s += __shfl_xor(s, m, 32);
                float avg = s * 0.025f;
                s_tenv[r * 64 + (hl ^ kt)] = f2bf(e1 - avg);
                if (hl < 8)        s_tenv[r * 64 + ((32 + hl) ^ kt)] = f2bf(e2 - avg);
                else if (hl == 8)  s_tenv[r * 64 + (40 ^ kt)]        = f2bf(avg);
                else               s_tenv[r * 64 + ((32 + hl) ^ kt)] = 0;   // cols 41..63 zero
            } else {
                s_tenv[r * 64 + (hl ^ kt)]        = 0;
                s_tenv[r * 64 + ((32 + hl) ^ kt)] = 0;
            }
        }
    }
    __syncthreads();

    const int cbase = lk * 8;

    // =========== stage B: hid = leaky(conv1f+conv1t); wave ct, loop 4 time tiles ===========
#pragma unroll 2
    for (int tile = 0; tile < 4; ++tile) {
        const int h0 = tile * 16;
        const int rF = h0 + lr;
        const unsigned short* F0 = s_feat + rF * 128;
        const unsigned short* F1 = s_feat + (rF + 1) * 128;
        const int kf0 = KF(rF), kf1 = KF(rF + 1);
        const unsigned short* E0 = s_tenv + rF * 64;
        const unsigned short* E1 = s_tenv + (rF + 1) * 64;
        const int kt0 = KT(rF), kt1 = KT(rF + 1);
        f32x4 acc0 = {0.f, 0.f, 0.f, 0.f};
        f32x4 acc1 = {0.f, 0.f, 0.f, 0.f};
#pragma unroll
        for (int s = 0; s < 4; ++s) {
            short8 a0 = *(const short8*)(F0 + ((cbase + 32 * s) ^ kf0));   // feat[t-1]
            short8 a1 = *(const short8*)(F1 + ((cbase + 32 * s) ^ kf1));   // feat[t]
            acc0 = __builtin_amdgcn_mfma_f32_16x16x32_bf16(a0, wB0[s], acc0, 0, 0, 0);
            acc1 = __builtin_amdgcn_mfma_f32_16x16x32_bf16(a1, wB1[s], acc1, 0, 0, 0);
        }
#pragma unroll
        for (int s = 0; s < 2; ++s) {
            short8 a0 = *(const short8*)(E0 + ((cbase + 32 * s) ^ kt0));
            short8 a1 = *(const short8*)(E1 + ((cbase + 32 * s) ^ kt1));
            acc0 = __builtin_amdgcn_mfma_f32_16x16x32_bf16(a0, wB0[4 + s], acc0, 0, 0, 0);
            acc1 = __builtin_amdgcn_mfma_f32_16x16x32_bf16(a1, wB1[4 + s], acc1, 0, 0, 0);
        }
#pragma unroll
        for (int j = 0; j < 4; ++j) {
            int h  = h0 + lk * 4 + j;
            int th = t0 - 16 + h;
            float v = acc0[j] + acc1[j] + bias1;
            v = v >= 0.f ? v : 0.2f * v;
            unsigned short u = (th >= 0) ? f2bf(v) : (unsigned short)0;
            if (ct < 8) s_hidA[h * 128 + ((ct * 16 + lr) ^ KA(h))] = u;
            else        s_hidB[h * 64 + (((ct - 8) * 16 + lr) ^ KB(h))] = u;
        }
    }
    __syncthreads();

    // =========== stage C: out = exp(conv2(hid)+b2)*x; wave ct, loop 3 time tiles ===========
#pragma unroll
    for (int tile = 0; tile < 3; ++tile) {
        const int r0 = 15 + tile * 16 + lr;
        const unsigned short* A0 = s_hidA + r0 * 128;
        const unsigned short* A1 = s_hidA + (r0 + 1) * 128;
        const int ka0 = KA(r0), ka1 = KA(r0 + 1);
        f32x4 acc0 = {0.f, 0.f, 0.f, 0.f};
        f32x4 acc1 = {0.f, 0.f, 0.f, 0.f};
#pragma unroll
        for (int s = 0; s < 4; ++s) {
            short8 a0 = *(const short8*)(A0 + ((cbase + 32 * s) ^ ka0));   // hid[t-1]
            short8 a1 = *(const short8*)(A1 + ((cbase + 32 * s) ^ ka1));   // hid[t]
            acc0 = __builtin_amdgcn_mfma_f32_16x16x32_bf16(a0, wC0[s], acc0, 0, 0, 0);
            acc1 = __builtin_amdgcn_mfma_f32_16x16x32_bf16(a1, wC1[s], acc1, 0, 0, 0);
        }
        {
            short8 a0 = *(const short8*)(s_hidB + r0 * 64 + (cbase ^ KB(r0)));
            short8 a1 = *(const short8*)(s_hidB + (r0 + 1) * 64 + (cbase ^ KB(r0 + 1)));
            acc0 = __builtin_amdgcn_mfma_f32_16x16x32_bf16(a0, wC0[4], acc0, 0, 0, 0);
            acc1 = __builtin_amdgcn_mfma_f32_16x16x32_bf16(a1, wC1[4], acc1, 0, 0, 0);
        }
#pragma unroll
        for (int j = 0; j < 4; ++j) {
            int t = t0 + tile * 16 + lk * 4 + j;
            if (t < TS) {
                size_t off = (size_t)b * NN + (size_t)t * 160 + ct * 16 + lr;
                out[off] = __expf(acc0[j] + acc1[j] + bias2) * x[off];
            }
        }
    }
}

extern "C" void kernel_launch(void* const* d_in, const int* in_sizes, int n_in,
                              void* d_out, int out_size, void* d_ws, size_t ws_size,
                              hipStream_t stream) {
    const float* x    = (const float*)d_in[0];
    const float* feat = (const float*)d_in[1];
    const float* W1f  = (const float*)d_in[2];
    const float* b1f  = (const float*)d_in[3];
    const float* W1t  = (const float*)d_in[4];
    const float* b1t  = (const float*)d_in[5];
    const float* W2   = (const float*)d_in[6];
    const float* b2   = (const float*)d_in[7];
    float* out = (float*)d_out;

    repack<<<(112960 + 255) / 256, 256, 0, stream>>>(W1f, b1f, W1t, b1t, W2, b2, d_ws);
    td_main<<<dim3(TB, BB), NTH, 0, stream>>>(
        x, feat, (const unsigned short*)d_ws, (const float*)d_ws, out);
}